// Round 14
// baseline (130.177 us; speedup 1.0000x reference)
//
#include <hip/hip_runtime.h>
#include <math.h>
#include <stdint.h>

// SemiConv2d tropical conv: out = max_{ic,kh,kw} min(x_pad, K). f16-packed.
// R14: early-exit with the overhead stripped. R13 (neutral) measured the exit
// point: ~150/288 taps (50% saved, cancelled by 2x per-tap overhead). Now:
// check every 16 taps (not 4), first 96 taps unconditional, uint2 table
// entries {k_dup, off|dw1bit} (half the s_load traffic, SALU decode), rotating
// 4-way sub-accs (1 pkmax/tap). Per tap: 1 dwordx2 + align + pkmin + pkmax.
// Exact: sorted desc => taps after exit have k <= k_next <= acc, cannot raise
// a max. Keep: xq 4-tap f16 ws (R7), inline-asm pk ops, hp-fastest blocks.
// NOTE: ~58us of dur_us is untouchable harness overhead (256MB ws poison
// fill ~43us + out fill + input restore + dispatch gaps).

#define HH 96
#define WW 96
#define CIN 32
#define OCN 32
#define XQ_ROWS 98
#define XQ_W 48
#define XQ_SLICE (XQ_ROWS * XQ_W)              // uint2 units per (n,ic) slice
#define XQ_TOTAL (256 * XQ_SLICE)              // uint2 elements
#define TB_TOTAL (32 * 288)                    // uint2 entries
#define WS_NEED ((size_t)XQ_TOTAL * 8 + (size_t)TB_TOTAL * 8)
#define NEGH2 0xFC00FC00u

typedef _Float16 h2 __attribute__((ext_vector_type(2)));
typedef uint32_t u2a4 __attribute__((ext_vector_type(2), aligned(4)));

__device__ __forceinline__ uint32_t pkmin_vs(uint32_t x, uint32_t k) {
    uint32_t d;
    asm("v_pk_min_f16 %0, %1, %2" : "=v"(d) : "v"(x), "s"(k));
    return d;
}
__device__ __forceinline__ uint32_t pkmin_vv(uint32_t a, uint32_t b) {
    uint32_t d;
    asm("v_pk_min_f16 %0, %1, %2" : "=v"(d) : "v"(a), "v"(b));
    return d;
}
__device__ __forceinline__ uint32_t pkmax(uint32_t a, uint32_t b) {
    uint32_t d;
    asm("v_pk_max_f16 %0, %1, %2" : "=v"(d) : "v"(a), "v"(b));
    return d;
}
__device__ __forceinline__ uint32_t packh2(float lo, float hi) {
    h2 p = {(_Float16)lo, (_Float16)hi};
    return __builtin_bit_cast(uint32_t, p);
}

// xq[(s*98 + rowpad)*48 + j] = 4xf16 (x[2j-1],x[2j] | x[2j+1],x[2j+2]), s=n*32+ic
__global__ __launch_bounds__(256) void setup_xq(const float* __restrict__ x,
                                                uint2* __restrict__ xq) {
    int idx = blockIdx.x * 256 + threadIdx.x;   // over 256*98*48 = 1,204,224
    int j  = idx % XQ_W;
    int t  = idx / XQ_W;
    int hp = t % XQ_ROWS;
    int s  = t / XQ_ROWS;
    int h  = hp - 1;
    bool hv = (h >= 0) && (h < HH);
    const float* row = x + ((size_t)s * HH + (hv ? h : 0)) * WW;
    float a = (hv && j > 0)        ? row[2 * j - 1] : -INFINITY;
    float b = hv                   ? row[2 * j]     : -INFINITY;
    float c = hv                   ? row[2 * j + 1] : -INFINITY;
    float d = (hv && j < XQ_W - 1) ? row[2 * j + 2] : -INFINITY;
    uint2 v;
    v.x = packh2(a, b);
    v.y = packh2(c, d);
    xq[idx] = v;
}

// per-oc tap table sorted by k DESC: entry {k_dup_f16, byte_off | (dw==1)}
__global__ void setup_tap(const float* __restrict__ kk, uint2* __restrict__ tbl) {
    __shared__ float ks[288];
    const int oc = blockIdx.x;                  // 32 blocks
    const int t  = threadIdx.x;                 // 288 threads
    float k = kk[oc * 288 + t];
    ks[t] = k;
    __syncthreads();
    int rank = 0;
    for (int s = 0; s < 288; ++s) {
        float kv = ks[s];
        rank += (kv > k) || (kv == k && s < t);
    }
    const int ic = t / 9, tap = t % 9, dh = tap / 3, dw = tap % 3;
    uint32_t off = (uint32_t)(ic * XQ_ROWS + dh) * (XQ_W * 8) + (dw == 2 ? 4u : 0u);
    uint32_t meta = off | (dw == 1 ? 1u : 0u);
    tbl[oc * 288 + rank] = make_uint2(packh2(k, k), meta);
}

__global__ __launch_bounds__(192, 8) void semiconv_ee(const char* __restrict__ xqb,
                                                      const uint2* __restrict__ tbl,
                                                      float* __restrict__ out) {
    const int tid = threadIdx.x;
    const int jj = tid % 48;          // w-pair 0..47
    const int hr = tid / 48;          // 0..3
    const int b  = blockIdx.x;
    const int hp = b % 24;            // hp FASTEST; XCD = hp%8 -> L2 locality
    const int t  = b / 24;
    const int oc = t & 31;
    const int n  = t >> 5;
    const int h  = hp * 4 + hr;       // one output row, 2 w (packed)

    const char* xb = xqb + (size_t)n * CIN * XQ_SLICE * 8;
    const int vbyte = (h * XQ_W + jj) * 8;
    const uint2* tb = tbl + oc * 288;

    uint32_t acc = NEGH2;

    for (int c = 0; c < 18; ++c) {                  // 18 chunks x 16 taps
        uint32_t a0 = NEGH2, a1 = NEGH2, a2 = NEGH2, a3 = NEGH2;
        const uint2* e = tb + c * 16;
#pragma unroll
        for (int i = 0; i < 4; ++i) {
            uint2 e0 = e[4 * i + 0], e1 = e[4 * i + 1];   // uniform -> s_load
            uint2 e2 = e[4 * i + 2], e3 = e[4 * i + 3];
            uint32_t o0 = e0.y & ~1u, s0 = (e0.y & 1u) << 4;
            uint32_t o1 = e1.y & ~1u, s1 = (e1.y & 1u) << 4;
            uint32_t o2 = e2.y & ~1u, s2 = (e2.y & 1u) << 4;
            uint32_t o3 = e3.y & ~1u, s3 = (e3.y & 1u) << 4;
            u2a4 q0 = *(const u2a4*)(xb + o0 + (uint32_t)vbyte);
            u2a4 q1 = *(const u2a4*)(xb + o1 + (uint32_t)vbyte);
            u2a4 q2 = *(const u2a4*)(xb + o2 + (uint32_t)vbyte);
            u2a4 q3 = *(const u2a4*)(xb + o3 + (uint32_t)vbyte);
            a0 = pkmax(a0, pkmin_vs(__builtin_amdgcn_alignbit(q0.y, q0.x, s0), e0.x));
            a1 = pkmax(a1, pkmin_vs(__builtin_amdgcn_alignbit(q1.y, q1.x, s1), e1.x));
            a2 = pkmax(a2, pkmin_vs(__builtin_amdgcn_alignbit(q2.y, q2.x, s2), e2.x));
            a3 = pkmax(a3, pkmin_vs(__builtin_amdgcn_alignbit(q3.y, q3.x, s3), e3.x));
        }
        acc = pkmax(acc, pkmax(pkmax(a0, a1), pkmax(a2, a3)));

        if (c >= 5 && c < 17) {       // check after >=96 taps, every 16 taps
            uint32_t kn = tb[16 * (c + 1)].x;         // max of remaining
            uint32_t sw = __builtin_amdgcn_alignbit(acc, acc, 16);
            uint32_t mn = pkmin_vv(acc, sw);
            h2 A  = __builtin_bit_cast(h2, mn);
            h2 KN = __builtin_bit_cast(h2, kn);
            if (__all((float)A.x >= (float)KN.x)) break;
        }
    }

    h2 a = __builtin_bit_cast(h2, acc);
    float2 v = make_float2((float)a.x, (float)a.y);
    *(float2*)(out + (((size_t)(n * OCN + oc)) * HH + h) * WW + 2 * jj) = v;
}

// ---------- f32 fallback if ws is too small ----------
#define NEGINF (-INFINITY)
__global__ __launch_bounds__(192, 8) void semiconv2d_f32(
    const float* __restrict__ x, const float* __restrict__ kk, float* __restrict__ out)
{
    const int tid = threadIdx.x;
    const int w  = tid % WW;
    const int hr = tid / WW;
    const int b   = blockIdx.x;
    const int ocb = b & 7;
    const int hp  = (b >> 3) % 48;
    const int n   = (b >> 3) / 48;
    const int h   = hp * 2 + hr;
    const int oc0 = ocb * 4;
    float a0[4], a1[4], a2[4];
#pragma unroll
    for (int i = 0; i < 4; ++i) { a0[i] = NEGINF; a1[i] = NEGINF; a2[i] = NEGINF; }
    const bool vm = (h > 0), vp = (h < HH - 1);
    const int hm  = vm ? h - 1 : h;
    const int hpl = vp ? h + 1 : h;
    const int cm  = (w > 0) ? -1 : 0;
    const int cp  = (w < WW - 1) ? 1 : 0;
    const float* rm = x + ((size_t)(n * CIN) * HH + hm)  * WW + w;
    const float* r1 = x + ((size_t)(n * CIN) * HH + h)   * WW + w;
    const float* rp = x + ((size_t)(n * CIN) * HH + hpl) * WW + w;
#pragma unroll 2
    for (int ic = 0; ic < CIN; ++ic) {
        float r00 = vm ? rm[cm] : NEGINF, r01 = vm ? rm[0] : NEGINF, r02 = vm ? rm[cp] : NEGINF;
        float r10 = r1[cm], r11 = r1[0], r12 = r1[cp];
        float r20 = vp ? rp[cm] : NEGINF, r21 = vp ? rp[0] : NEGINF, r22 = vp ? rp[cp] : NEGINF;
#pragma unroll
        for (int oc = 0; oc < 4; ++oc) {
            const float* kq = kk + (size_t)(((oc0 + oc) * CIN + ic)) * 9;
            a0[oc] = fmaxf(fmaxf(a0[oc], fminf(r00, kq[0])), fmaxf(fminf(r10, kq[3]), fminf(r20, kq[6])));
            a1[oc] = fmaxf(fmaxf(a1[oc], fminf(r01, kq[1])), fmaxf(fminf(r11, kq[4]), fminf(r21, kq[7])));
            a2[oc] = fmaxf(fmaxf(a2[oc], fminf(r02, kq[2])), fmaxf(fminf(r12, kq[5]), fminf(r22, kq[8])));
        }
        rm += HH * WW; r1 += HH * WW; rp += HH * WW;
    }
#pragma unroll
    for (int oc = 0; oc < 4; ++oc) {
        float v0 = (w > 0)      ? a0[oc] : NEGINF;
        float v2 = (w < WW - 1) ? a2[oc] : NEGINF;
        out[(((size_t)(n * OCN + oc0 + oc)) * HH + h) * WW + w] = fmaxf(fmaxf(v0, a1[oc]), v2);
    }
}

extern "C" void kernel_launch(void* const* d_in, const int* in_sizes, int n_in,
                              void* d_out, int out_size, void* d_ws, size_t ws_size,
                              hipStream_t stream) {
    const float* x  = (const float*)d_in[0];
    const float* kk = (const float*)d_in[1];
    float* out      = (float*)d_out;
    if (ws_size >= WS_NEED) {
        uint2* xq  = (uint2*)d_ws;
        uint2* tbl = (uint2*)((char*)d_ws + (size_t)XQ_TOTAL * 8);
        setup_xq<<<dim3(XQ_TOTAL / 256), dim3(256), 0, stream>>>(x, xq);
        setup_tap<<<dim3(32), dim3(288), 0, stream>>>(kk, tbl);
        semiconv_ee<<<dim3(8 * 32 * 24), dim3(192), 0, stream>>>(
            (const char*)xq, tbl, out);
    } else {
        semiconv2d_f32<<<dim3(8 * 48 * 8), dim3(192), 0, stream>>>(x, kk, out);
    }
}

// Round 15
// 104.460 us; speedup vs baseline: 1.2462x; 1.2462x over previous
//
#include <hip/hip_runtime.h>
#include <math.h>
#include <stdint.h>

// SemiConv2d tropical conv: out = max_{ic,kh,kw} min(x_pad, K). f16-packed.
// R15: ic-granular early exit on R12's proven lean body. R14 post-mortem:
// tap-granular sorted scan DID exit at ~160/288 taps (per-wave VALU ~800
// instr) but lost 1.4x to load serialization (1 load/tap vs 0.33, VGPR=20).
// Here the per-ic body is byte-identical to R12 (3 dwordx2 + 3 alignbit +
// 18 pkmin_vs + tree, per-ic K s_load); additions: ic order from a 32-entry
// sorted table (uint2 s_load/ic), exit check every 2 ics after 8 (~3%
// overhead). Exact: M_f16 = max(f16 taps) (monotone rounding); exit =>
// remaining min(x,k) <= k <= M <= acc. Keep: xq ws, inline-asm pk ops,
// hp-fastest blocks, launch_bounds(192,8), grid 8x24x16.
// NOTE: ~58us of dur_us is untouchable harness overhead (256MB ws fill etc).

#define HH 96
#define WW 96
#define CIN 32
#define OCN 32
#define XQ_ROWS 98
#define XQ_W 48
#define XQ_SLICE (XQ_ROWS * XQ_W)              // uint2 units per (n,ic) slice
#define XQ_TOTAL (256 * XQ_SLICE)              // uint2 elements
#define K2_TOTAL (16 * 32 * 2 * 9)             // uint32 elements
#define TB_TOTAL (16 * 32)                     // uint2 elements
#define WS_NEED ((size_t)XQ_TOTAL * 8 + (size_t)K2_TOTAL * 4 + (size_t)TB_TOTAL * 8)
#define NEGH2 0xFC00FC00u

typedef _Float16 h2 __attribute__((ext_vector_type(2)));

__device__ __forceinline__ uint32_t pkmin_vs(uint32_t x, uint32_t k) {
    uint32_t d;
    asm("v_pk_min_f16 %0, %1, %2" : "=v"(d) : "v"(x), "s"(k));
    return d;
}
__device__ __forceinline__ uint32_t pkmin_vv(uint32_t a, uint32_t b) {
    uint32_t d;
    asm("v_pk_min_f16 %0, %1, %2" : "=v"(d) : "v"(a), "v"(b));
    return d;
}
__device__ __forceinline__ uint32_t pkmax(uint32_t a, uint32_t b) {
    uint32_t d;
    asm("v_pk_max_f16 %0, %1, %2" : "=v"(d) : "v"(a), "v"(b));
    return d;
}
__device__ __forceinline__ uint32_t packh2(float lo, float hi) {
    h2 p = {(_Float16)lo, (_Float16)hi};
    return __builtin_bit_cast(uint32_t, p);
}

// xq[(s*98 + rowpad)*48 + j] = 4xf16 (x[2j-1],x[2j] | x[2j+1],x[2j+2]), s=n*32+ic
__global__ __launch_bounds__(256) void setup_xq(const float* __restrict__ x,
                                                uint2* __restrict__ xq) {
    int idx = blockIdx.x * 256 + threadIdx.x;   // over 256*98*48 = 1,204,224
    int j  = idx % XQ_W;
    int t  = idx / XQ_W;
    int hp = t % XQ_ROWS;
    int s  = t / XQ_ROWS;
    int h  = hp - 1;
    bool hv = (h >= 0) && (h < HH);
    const float* row = x + ((size_t)s * HH + (hv ? h : 0)) * WW;
    float a = (hv && j > 0)        ? row[2 * j - 1] : -INFINITY;
    float b = hv                   ? row[2 * j]     : -INFINITY;
    float c = hv                   ? row[2 * j + 1] : -INFINITY;
    float d = (hv && j < XQ_W - 1) ? row[2 * j + 2] : -INFINITY;
    uint2 v;
    v.x = packh2(a, b);
    v.y = packh2(c, d);
    xq[idx] = v;
}

// k2[ocb(16)][ic(32)][oc2(2)][9] duplicated f16 pairs
__global__ __launch_bounds__(256) void setup_k(const float* __restrict__ kk,
                                               uint32_t* __restrict__ k2) {
    int idx = blockIdx.x * 256 + threadIdx.x;   // over 9216
    int tap = idx % 9;
    int oc2 = (idx / 9) % 2;
    int ic  = (idx / 18) % CIN;
    int ocb = idx / (18 * CIN);
    float v = kk[(((ocb * 2 + oc2) * CIN) + ic) * 9 + tap];
    k2[idx] = packh2(v, v);
}

// per-ocb ic table sorted desc by M[ic] = max of the pair's 18 f16 taps
__global__ void setup_tbl(const float* __restrict__ kk, uint2* __restrict__ tbl) {
    __shared__ float ms[32];
    const int ocb = blockIdx.x;                 // 16 blocks
    const int ic  = threadIdx.x;                // 32 threads
    float m = -INFINITY;
    for (int oc = 0; oc < 2; ++oc)
        for (int t = 0; t < 9; ++t)
            m = fmaxf(m, kk[(((ocb * 2 + oc) * CIN) + ic) * 9 + t]);
    ms[ic] = m;
    __syncthreads();
    int rank = 0;
    for (int s = 0; s < 32; ++s) {
        float v = ms[s];
        rank += (v > m) || (v == m && s < ic);
    }
    // f16 pack is monotone: f16(max k) == max(f16 k)
    tbl[ocb * 32 + rank] = make_uint2(packh2(m, m), (uint32_t)ic);
}

__global__ __launch_bounds__(192, 8) void semiconv_ic_ee(const uint2* __restrict__ xq,
                                                         const uint32_t* __restrict__ k2,
                                                         const uint2* __restrict__ tbl,
                                                         float* __restrict__ out) {
    const int tid = threadIdx.x;
    const int jj = tid % 48;          // w-pair 0..47
    const int hr = tid / 48;          // 0..3
    const int b  = blockIdx.x;
    const int hp  = b % 24;           // hp FASTEST; XCD = hp%8 -> L2 locality
    const int t   = b / 24;
    const int ocb = t & 15;           // oc-pair
    const int n   = t >> 4;
    const int h   = hp * 4 + hr;      // one output row per thread (2 w packed)

    // xq base for this (n, h): slice offset added per sorted ic
    const uint2* xb = xq + (size_t)(n * CIN) * XQ_SLICE + h * XQ_W + jj;
    const uint32_t* kp = k2 + (size_t)ocb * CIN * 18;
    const uint2* tb = tbl + ocb * 32;

    uint32_t acc[2] = {NEGH2, NEGH2};

    for (int cc = 0; cc < 16; ++cc) {           // 2 sorted ics per step
        uint2 e0 = tb[2 * cc], e1 = tb[2 * cc + 1];      // uniform -> s_load
        const uint32_t ic0 = e0.y, ic1 = e1.y;

        uint2 q[2][3];
#pragma unroll
        for (int r = 0; r < 3; ++r) {
            q[0][r] = xb[(size_t)ic0 * XQ_SLICE + r * XQ_W];
            q[1][r] = xb[(size_t)ic1 * XQ_SLICE + r * XQ_W];
        }

#pragma unroll
        for (int u = 0; u < 2; ++u) {
            uint32_t tap[9];
#pragma unroll
            for (int r = 0; r < 3; ++r) {
                tap[r * 3 + 0] = q[u][r].x;
                tap[r * 3 + 1] = __builtin_amdgcn_alignbit(q[u][r].y, q[u][r].x, 16);
                tap[r * 3 + 2] = q[u][r].y;
            }
            const uint32_t* kq0 = kp + (u ? ic1 : ic0) * 18;
#pragma unroll
            for (int oc = 0; oc < 2; ++oc) {
                const uint32_t* kq = kq0 + oc * 9;       // uniform -> s_load
                uint32_t m0 = pkmin_vs(tap[0], kq[0]);
                uint32_t m1 = pkmin_vs(tap[1], kq[1]);
                uint32_t m2 = pkmin_vs(tap[2], kq[2]);
                uint32_t m3 = pkmin_vs(tap[3], kq[3]);
                uint32_t m4 = pkmin_vs(tap[4], kq[4]);
                uint32_t m5 = pkmin_vs(tap[5], kq[5]);
                uint32_t m6 = pkmin_vs(tap[6], kq[6]);
                uint32_t m7 = pkmin_vs(tap[7], kq[7]);
                uint32_t m8 = pkmin_vs(tap[8], kq[8]);
                uint32_t t01 = pkmax(m0, m1), t23 = pkmax(m2, m3);
                uint32_t t45 = pkmax(m4, m5), t67 = pkmax(m6, m7);
                uint32_t tt  = pkmax(pkmax(t01, t23), pkmax(t45, t67));
                acc[oc] = pkmax(acc[oc], pkmax(tt, m8));
            }
        }

        if (cc >= 4 && cc < 15) {     // exit check after >=10 ics, every 2 ics
            uint32_t kn = tb[2 * (cc + 1)].x;            // max remaining M
            uint32_t mn = pkmin_vv(acc[0], acc[1]);
            mn = pkmin_vv(mn, __builtin_amdgcn_alignbit(mn, mn, 16));
            h2 A  = __builtin_bit_cast(h2, mn);
            h2 KN = __builtin_bit_cast(h2, kn);
            if (__all((float)A.x >= (float)KN.x)) break;
        }
    }

#pragma unroll
    for (int oc = 0; oc < 2; ++oc) {
        h2 a = __builtin_bit_cast(h2, acc[oc]);
        float2 v = make_float2((float)a.x, (float)a.y);
        *(float2*)(out + (((size_t)(n * OCN + ocb * 2 + oc)) * HH + h) * WW + 2 * jj) = v;
    }
}

// ---------- f32 fallback if ws is too small ----------
#define NEGINF (-INFINITY)
__global__ __launch_bounds__(192, 8) void semiconv2d_f32(
    const float* __restrict__ x, const float* __restrict__ kk, float* __restrict__ out)
{
    const int tid = threadIdx.x;
    const int w  = tid % WW;
    const int hr = tid / WW;
    const int b   = blockIdx.x;
    const int ocb = b & 7;
    const int hp  = (b >> 3) % 48;
    const int n   = (b >> 3) / 48;
    const int h   = hp * 2 + hr;
    const int oc0 = ocb * 4;
    float a0[4], a1[4], a2[4];
#pragma unroll
    for (int i = 0; i < 4; ++i) { a0[i] = NEGINF; a1[i] = NEGINF; a2[i] = NEGINF; }
    const bool vm = (h > 0), vp = (h < HH - 1);
    const int hm  = vm ? h - 1 : h;
    const int hpl = vp ? h + 1 : h;
    const int cm  = (w > 0) ? -1 : 0;
    const int cp  = (w < WW - 1) ? 1 : 0;
    const float* rm = x + ((size_t)(n * CIN) * HH + hm)  * WW + w;
    const float* r1 = x + ((size_t)(n * CIN) * HH + h)   * WW + w;
    const float* rp = x + ((size_t)(n * CIN) * HH + hpl) * WW + w;
#pragma unroll 2
    for (int ic = 0; ic < CIN; ++ic) {
        float r00 = vm ? rm[cm] : NEGINF, r01 = vm ? rm[0] : NEGINF, r02 = vm ? rm[cp] : NEGINF;
        float r10 = r1[cm], r11 = r1[0], r12 = r1[cp];
        float r20 = vp ? rp[cm] : NEGINF, r21 = vp ? rp[0] : NEGINF, r22 = vp ? rp[cp] : NEGINF;
#pragma unroll
        for (int oc = 0; oc < 4; ++oc) {
            const float* kq = kk + (size_t)(((oc0 + oc) * CIN + ic)) * 9;
            a0[oc] = fmaxf(fmaxf(a0[oc], fminf(r00, kq[0])), fmaxf(fminf(r10, kq[3]), fminf(r20, kq[6])));
            a1[oc] = fmaxf(fmaxf(a1[oc], fminf(r01, kq[1])), fmaxf(fminf(r11, kq[4]), fminf(r21, kq[7])));
            a2[oc] = fmaxf(fmaxf(a2[oc], fminf(r02, kq[2])), fmaxf(fminf(r12, kq[5]), fminf(r22, kq[8])));
        }
        rm += HH * WW; r1 += HH * WW; rp += HH * WW;
    }
#pragma unroll
    for (int oc = 0; oc < 4; ++oc) {
        float v0 = (w > 0)      ? a0[oc] : NEGINF;
        float v2 = (w < WW - 1) ? a2[oc] : NEGINF;
        out[(((size_t)(n * OCN + oc0 + oc)) * HH + h) * WW + w] = fmaxf(fmaxf(v0, a1[oc]), v2);
    }
}

extern "C" void kernel_launch(void* const* d_in, const int* in_sizes, int n_in,
                              void* d_out, int out_size, void* d_ws, size_t ws_size,
                              hipStream_t stream) {
    const float* x  = (const float*)d_in[0];
    const float* kk = (const float*)d_in[1];
    float* out      = (float*)d_out;
    if (ws_size >= WS_NEED) {
        uint2* xq    = (uint2*)d_ws;
        uint32_t* k2 = (uint32_t*)((char*)d_ws + (size_t)XQ_TOTAL * 8);
        uint2* tbl   = (uint2*)((char*)d_ws + (size_t)XQ_TOTAL * 8 + (size_t)K2_TOTAL * 4);
        setup_xq<<<dim3(XQ_TOTAL / 256), dim3(256), 0, stream>>>(x, xq);
        setup_k<<<dim3(K2_TOTAL / 256), dim3(256), 0, stream>>>(kk, k2);
        setup_tbl<<<dim3(16), dim3(32), 0, stream>>>(kk, tbl);
        semiconv_ic_ee<<<dim3(8 * 16 * 24), dim3(192), 0, stream>>>(xq, k2, tbl, out);
    } else {
        semiconv2d_f32<<<dim3(8 * 48 * 8), dim3(192), 0, stream>>>(x, kk, out);
    }
}